// Round 16
// baseline (226.322 us; speedup 1.0000x reference)
//
#include <hip/hip_runtime.h>
#include <hip/hip_bf16.h>

// Problem constants
#define BT 2048   // batch
#define DD 512    // input dim
#define HH 512    // hidden dim
#define EE 32     // experts
#define KK 4      // top-k
#define CHN 32    // confidence hidden
#define MAXCH 160 // max 64-row chunks: 8192/64 + 32

// prep: cvt_x (512) | tr_wc (272: 34 imgs incl Wg2 hi/lo) | tr_w (66 z x 32)
#define NB_CVT 512
#define NB_TRWC 272
#define NB_TRW 2112
#define NB_PREP (NB_CVT + NB_TRWC + NB_TRW)

typedef unsigned int u32;
typedef unsigned short u16;
typedef __attribute__((ext_vector_type(8))) short short8;
typedef __attribute__((ext_vector_type(4))) float f32x4;
typedef __attribute__((ext_vector_type(2))) u32 u32x2;
typedef __attribute__((ext_vector_type(4))) u32 u32x4;

__device__ inline u16 f2bf(float f) {  // RNE float->bf16
  u32 u = __builtin_bit_cast(u32, f);
  u32 r = (u + 0x7FFFu + ((u >> 16) & 1u)) >> 16;
  return (u16)r;
}
__device__ inline float bf16f(u16 b) {  // bf16 -> float
  u32 u = ((u32)b) << 16;
  return __builtin_bit_cast(float, u);
}
__device__ inline u32 pack2bf(float a, float b) {
  return (u32)f2bf(a) | ((u32)f2bf(b) << 16);
}
__device__ inline void gload_lds16(const u32* g, u32* l) {
  __builtin_amdgcn_global_load_lds((const __attribute__((address_space(1))) u32*)g,
                                   (__attribute__((address_space(3))) u32*)l, 16, 0, 0);
}

// ---------------------------------------------------------------------------
// Fused prep (pure streaming, no LDS):
//  cvt_x: x -> bf16 hi (xh) + bf16 residual lo (xl)
//  tr_wc: Wc1 (e 0..31) + Wg2-hi (e=32) + Wg2-lo (e=33) conf-style images
//  tr_w:  z 0..31 W1 | 32..63 W2 | 64 Wg1-hi | 65 Wg1-lo  -> fraglet images
// ---------------------------------------------------------------------------
__global__ __launch_bounds__(256)
void k_prep(const float* __restrict__ x, const float* __restrict__ W1,
            const float* __restrict__ W2, const float* __restrict__ Wc1,
            const float* __restrict__ Wg1, const float* __restrict__ Wg2,
            u16* __restrict__ xh, u16* __restrict__ xl,
            u32* __restrict__ img, u32* __restrict__ img_c) {
  const int bx = blockIdx.x;
  const int tid = threadIdx.x;
  if (bx < NB_CVT) {
    // ---- cvt_x: hi + residual-lo ----
    int gid = bx * 256 + tid;
    const float4* src = reinterpret_cast<const float4*>(x) + (size_t)gid * 2;
    float4 a = src[0], b = src[1];
    u32x4 hi = { pack2bf(a.x, a.y), pack2bf(a.z, a.w),
                 pack2bf(b.x, b.y), pack2bf(b.z, b.w) };
    float lx0 = a.x - bf16f(f2bf(a.x)), lx1 = a.y - bf16f(f2bf(a.y));
    float lx2 = a.z - bf16f(f2bf(a.z)), lx3 = a.w - bf16f(f2bf(a.w));
    float lx4 = b.x - bf16f(f2bf(b.x)), lx5 = b.y - bf16f(f2bf(b.y));
    float lx6 = b.z - bf16f(f2bf(b.z)), lx7 = b.w - bf16f(f2bf(b.w));
    u32x4 lo = { pack2bf(lx0, lx1), pack2bf(lx2, lx3),
                 pack2bf(lx4, lx5), pack2bf(lx6, lx7) };
    reinterpret_cast<u32x4*>(xh)[gid] = hi;
    reinterpret_cast<u32x4*>(xl)[gid] = lo;
  } else if (bx < NB_CVT + NB_TRWC) {
    // ---- tr_wc: [512][32] fp32 -> k-major fraglet image (Wc1 / Wg2 hi/lo) --
    int idx = (bx - NB_CVT) * 2 + (tid >> 7);   // 0..543
    int e = idx >> 4, s = idx & 15;
    int t127 = tid & 127;
    int q = t127 >> 5, col = t127 & 31;
    const float* W = (e < EE) ? (Wc1 + (size_t)e * DD * CHN) : Wg2;
    float v[8];
#pragma unroll
    for (int j = 0; j < 8; ++j)
      v[j] = W[(size_t)(s * 32 + q * 8 + j) * CHN + col];
    if (e == 33) {
#pragma unroll
      for (int j = 0; j < 8; ++j)
        v[j] = v[j] - bf16f(f2bf(v[j]));      // exact residual
    }
    u32x4 fr = { pack2bf(v[0], v[1]), pack2bf(v[2], v[3]),
                 pack2bf(v[4], v[5]), pack2bf(v[6], v[7]) };
    *reinterpret_cast<u32x4*>(img_c + ((size_t)e * 16 + s) * 512 + q * 128 + col * 4) = fr;
  } else {
    // ---- tr_w: weight fraglet images (incl. Wg1 hi/lo at z=64/65) ----
    int u = bx - (NB_CVT + NB_TRWC);
    int z = u >> 5;
    int s = (u >> 1) & 15;
    int n = (u & 1) * 256 + tid;
    const float* W = (z < EE) ? (W1 + (size_t)z * DD * HH)
                   : (z < 2 * EE) ? (W2 + (size_t)(z - EE) * HH * DD)
                   : Wg1;
    float v[32];
#pragma unroll
    for (int k = 0; k < 32; k++)
      v[k] = W[(size_t)(s * 32 + k) * 512 + n];
    if (z == 65) {
#pragma unroll
      for (int k = 0; k < 32; k++)
        v[k] = v[k] - bf16f(f2bf(v[k]));
    }
    int nc = n >> 7, coll = n & 127;
    u32* ob = img + ((size_t)(z * 4 + nc) * 16 + s) * 2048 + coll * 4;
#pragma unroll
    for (int g = 0; g < 4; g++) {
      u32x4 fr = { pack2bf(v[g * 8 + 0], v[g * 8 + 1]),
                   pack2bf(v[g * 8 + 2], v[g * 8 + 3]),
                   pack2bf(v[g * 8 + 4], v[g * 8 + 5]),
                   pack2bf(v[g * 8 + 6], v[g * 8 + 7]) };
      *reinterpret_cast<u32x4*>(ob + g * 512) = fr;
    }
  }
}

// ---------------------------------------------------------------------------
// Fused gate + route + build. Grid (32 chunks, 8 h-chunks), 256 thr, 64KB LDS.
// Phase 1 (all): gate MFMA tile (64h x 64t) -> hh/hl split bf16.
// Phase 2 (per-chunk winner via done1): route logits+softmax+top4 for chunk.
// Phase 3 (global winner via gdone): build tlist/cnt/chunk tables.
// ---------------------------------------------------------------------------
__global__ __launch_bounds__(256)
void k_gate_fused(const u16* __restrict__ xh, const u16* __restrict__ xl,
                  const u32* __restrict__ img, const float* __restrict__ bg1,
                  const u32* __restrict__ img_c, const float* __restrict__ bg2,
                  u16* __restrict__ hh, u16* __restrict__ hl,
                  float* __restrict__ wts, int* __restrict__ topi,
                  int* __restrict__ done1, int* __restrict__ gdone,
                  int* __restrict__ cnt, int* __restrict__ tlist,
                  int* __restrict__ chunk2e, int* __restrict__ chunkloc) {
  __shared__ u32 smem[16384];   // 64 KB union
  __shared__ int winflag, bwin;
  const int chunk = blockIdx.x;
  const int hc = blockIdx.y;
  const int tid = threadIdx.x;
  const int w = tid >> 6, lane = tid & 63;
  const int l15 = lane & 15, q = lane >> 4;
  const int wm = w & 1, wn = w >> 1;

  // ---------------- phase 1: gate MFMA ----------------
  {
    auto S = [&](int b, int h2) { return smem + (b * 2 + h2) * 1024; };
    const int nc = hc >> 1, co = (hc & 1) * 64;
    const u32* imgh = img + ((size_t)(64 * 4 + nc) * 16) * 2048;
    const u32* imgl = img + ((size_t)(65 * 4 + nc) * 16) * 2048;
    const int sq = tid >> 6, scol = tid & 63;
    auto stage = [&](int s, int b) {
      gload_lds16(imgh + s * 2048 + sq * 512 + (co + scol) * 4, S(b, 0) + tid * 4);
      gload_lds16(imgl + s * 2048 + sq * 512 + (co + scol) * 4, S(b, 1) + tid * 4);
    };
    const int t0 = chunk * 64 + wn * 32 + l15;
    const int t1 = t0 + 16;
    auto ldb = [&](const u16* src, int t, int s) {
      return *reinterpret_cast<const short8*>(src + (size_t)t * 512 + s * 32 + q * 8);
    };

    f32x4 acc[2][2];
#pragma unroll
    for (int a = 0; a < 2; a++)
#pragma unroll
      for (int b = 0; b < 2; b++) acc[a][b] = {0.f, 0.f, 0.f, 0.f};

    stage(0, 0);
    short8 bh[2], bl[2];
    bh[0] = ldb(xh, t0, 0); bh[1] = ldb(xh, t1, 0);
    bl[0] = ldb(xl, t0, 0); bl[1] = ldb(xl, t1, 0);
    __syncthreads();

    for (int s = 0; s < 16; ++s) {
      const u32* ch = S(s & 1, 0);
      const u32* cl = S(s & 1, 1);
      short8 nh[2], nl[2];
      if (s < 15) {
        stage(s + 1, (s + 1) & 1);
        nh[0] = ldb(xh, t0, s + 1); nh[1] = ldb(xh, t1, s + 1);
        nl[0] = ldb(xl, t0, s + 1); nl[1] = ldb(xl, t1, s + 1);
      }
#pragma unroll
      for (int mf = 0; mf < 2; ++mf) {
        int col = wm * 32 + mf * 16 + l15;
        short8 ah = *reinterpret_cast<const short8*>(ch + q * 256 + col * 4);
        short8 al = *reinterpret_cast<const short8*>(cl + q * 256 + col * 4);
#pragma unroll
        for (int nf = 0; nf < 2; ++nf) {
          acc[mf][nf] = __builtin_amdgcn_mfma_f32_16x16x32_bf16(ah, bh[nf], acc[mf][nf], 0, 0, 0);
          acc[mf][nf] = __builtin_amdgcn_mfma_f32_16x16x32_bf16(ah, bl[nf], acc[mf][nf], 0, 0, 0);
          acc[mf][nf] = __builtin_amdgcn_mfma_f32_16x16x32_bf16(al, bh[nf], acc[mf][nf], 0, 0, 0);
          acc[mf][nf] = __builtin_amdgcn_mfma_f32_16x16x32_bf16(al, bl[nf], acc[mf][nf], 0, 0, 0);
        }
      }
      __syncthreads();
      if (s < 15) {
        bh[0] = nh[0]; bh[1] = nh[1];
        bl[0] = nl[0]; bl[1] = nl[1];
      }
    }

    // epilogue: bias + relu -> split bf16 hi/lo
#pragma unroll
    for (int mf = 0; mf < 2; ++mf) {
      int hcol = hc * 64 + wm * 32 + mf * 16 + q * 4;
      float4 bb = *reinterpret_cast<const float4*>(&bg1[hcol]);
#pragma unroll
      for (int nf = 0; nf < 2; ++nf) {
        int t = chunk * 64 + wn * 32 + nf * 16 + l15;
        float v0 = fmaxf(acc[mf][nf].x + bb.x, 0.f);
        float v1 = fmaxf(acc[mf][nf].y + bb.y, 0.f);
        float v2 = fmaxf(acc[mf][nf].z + bb.z, 0.f);
        float v3 = fmaxf(acc[mf][nf].w + bb.w, 0.f);
        u32x2 hi = { pack2bf(v0, v1), pack2bf(v2, v3) };
        float r0 = v0 - bf16f(f2bf(v0)), r1 = v1 - bf16f(f2bf(v1));
        float r2 = v2 - bf16f(f2bf(v2)), r3 = v3 - bf16f(f2bf(v3));
        u32x2 lo = { pack2bf(r0, r1), pack2bf(r2, r3) };
        *reinterpret_cast<u32x2*>(hh + (size_t)t * 512 + hcol) = hi;
        *reinterpret_cast<u32x2*>(hl + (size_t)t * 512 + hcol) = lo;
      }
    }
  }

  // ---------------- winner election for route ----------------
  __threadfence();
  if (tid == 0) winflag = (atomicAdd(&done1[chunk], 1) == 7);
  __syncthreads();
  if (!winflag) return;
  __threadfence();

  // ---------------- phase 2: route (chunk winner) ----------------
  {
    u32* sh = smem;          // Wg2-hi image (32 KB)
    u32* sl_ = smem + 8192;  // Wg2-lo image (32 KB)
    const u32* srch = img_c + (size_t)32 * 16 * 512;
    const u32* srcl = img_c + (size_t)33 * 16 * 512;
#pragma unroll
    for (int i = 0; i < 8; ++i) {
      gload_lds16(srch + tid * 4 + i * 1024, sh + tid * 4 + i * 1024);
      gload_lds16(srcl + tid * 4 + i * 1024, sl_ + tid * 4 + i * 1024);
    }
    __syncthreads();

    const int t = chunk * 64 + w * 16 + l15;
    const u16* rh = hh + (size_t)t * 512;
    const u16* rl = hl + (size_t)t * 512;
    f32x4 acc0 = {0.f, 0.f, 0.f, 0.f}, acc1 = {0.f, 0.f, 0.f, 0.f};
#pragma unroll
    for (int st = 0; st < 16; ++st) {
      short8 bh = *reinterpret_cast<const short8*>(rh + st * 32 + q * 8);
      short8 bl = *reinterpret_cast<const short8*>(rl + st * 32 + q * 8);
      short8 ah0 = *reinterpret_cast<const short8*>(sh + st * 512 + q * 128 + l15 * 4);
      short8 ah1 = *reinterpret_cast<const short8*>(sh + st * 512 + q * 128 + (16 + l15) * 4);
      short8 al0 = *reinterpret_cast<const short8*>(sl_ + st * 512 + q * 128 + l15 * 4);
      short8 al1 = *reinterpret_cast<const short8*>(sl_ + st * 512 + q * 128 + (16 + l15) * 4);
      acc0 = __builtin_amdgcn_mfma_f32_16x16x32_bf16(ah0, bh, acc0, 0, 0, 0);
      acc0 = __builtin_amdgcn_mfma_f32_16x16x32_bf16(ah0, bl, acc0, 0, 0, 0);
      acc0 = __builtin_amdgcn_mfma_f32_16x16x32_bf16(al0, bh, acc0, 0, 0, 0);
      acc0 = __builtin_amdgcn_mfma_f32_16x16x32_bf16(al0, bl, acc0, 0, 0, 0);
      acc1 = __builtin_amdgcn_mfma_f32_16x16x32_bf16(ah1, bh, acc1, 0, 0, 0);
      acc1 = __builtin_amdgcn_mfma_f32_16x16x32_bf16(ah1, bl, acc1, 0, 0, 0);
      acc1 = __builtin_amdgcn_mfma_f32_16x16x32_bf16(al1, bh, acc1, 0, 0, 0);
      acc1 = __builtin_amdgcn_mfma_f32_16x16x32_bf16(al1, bl, acc1, 0, 0, 0);
    }

    float lv[8];
    int li[8];
#pragma unroll
    for (int i = 0; i < 4; ++i) {
      li[i] = q * 4 + i;
      lv[i] = acc0[i] + bg2[li[i]];
      li[4 + i] = 16 + q * 4 + i;
      lv[4 + i] = acc1[i] + bg2[li[4 + i]];
    }
    float mx = lv[0];
#pragma unroll
    for (int k = 1; k < 8; ++k) mx = fmaxf(mx, lv[k]);
    mx = fmaxf(mx, __shfl_xor(mx, 16));
    mx = fmaxf(mx, __shfl_xor(mx, 32));
    float ex[8], sm = 0.f;
#pragma unroll
    for (int k = 0; k < 8; ++k) { ex[k] = expf(lv[k] - mx); sm += ex[k]; }
    sm += __shfl_xor(sm, 16);
    sm += __shfl_xor(sm, 32);
    float inv = 1.f / sm;
    float4 w0 = { ex[0] * inv, ex[1] * inv, ex[2] * inv, ex[3] * inv };
    float4 w1 = { ex[4] * inv, ex[5] * inv, ex[6] * inv, ex[7] * inv };
    *reinterpret_cast<float4*>(&wts[(size_t)t * EE + q * 4]) = w0;
    *reinterpret_cast<float4*>(&wts[(size_t)t * EE + 16 + q * 4]) = w1;
    unsigned used = 0;
    for (int j = 0; j < KK; ++j) {
      float bv = -1e30f;
      int bi = 64;
#pragma unroll
      for (int k = 0; k < 8; ++k) {
        if (!((used >> k) & 1u) && (lv[k] > bv || (lv[k] == bv && li[k] < bi))) {
          bv = lv[k]; bi = li[k];
        }
      }
#pragma unroll
      for (int m = 16; m <= 32; m <<= 1) {
        float ov = __shfl_xor(bv, m);
        int oi = __shfl_xor(bi, m);
        if (ov > bv || (ov == bv && oi < bi)) { bv = ov; bi = oi; }
      }
      if (q == 0) topi[(t << 2) | j] = bi;
#pragma unroll
      for (int k = 0; k < 8; ++k)
        if (li[k] == bi) used |= 1u << k;
    }
  }

  // ---------------- winner election for build ----------------
  __threadfence();
  if (tid == 0) bwin = (atomicAdd(gdone, 1) == 31);
  __syncthreads();
  if (!bwin) return;
  __threadfence();

  // ---------------- phase 3: build (global winner) ----------------
  {
    int* lcnt = (int*)smem;
    if (tid < EE) lcnt[tid] = 0;
    __syncthreads();
    for (int i = tid; i < BT * KK; i += 256) {
      int e2 = topi[i];
      int pos = atomicAdd(&lcnt[e2], 1);
      tlist[(size_t)e2 * BT + pos] = i;
    }
    __syncthreads();
    if (tid < EE) {
      int e2 = tid;
      cnt[e2] = lcnt[e2];
      int off = 0, tot = 0;
      for (int j = 0; j < EE; ++j) {
        int nj = (lcnt[j] + 63) >> 6;
        if (j < e2) off += nj;
        tot += nj;
      }
      int myn = (lcnt[e2] + 63) >> 6;
      for (int j = 0; j < myn; ++j) {
        chunk2e[off + j] = e2; chunkloc[off + j] = j;
      }
      for (int idx = tot + e2; idx < MAXCH; idx += EE) {
        chunk2e[idx] = -1; chunkloc[idx] = 0;
      }
    }
  }
}

// XCD-affinity chunk remap.
__device__ inline int remap_chunk(int bx) {
  return (bx & 7) * (MAXCH / 8) + (bx >> 3);
}

// ---------------------------------------------------------------------------
// GEMM1 (grouped, swapped): hidT = W1T(512h x 512k) . xT(512k x 64t).
// ---------------------------------------------------------------------------
__global__ __launch_bounds__(256)
void k_gemm1(const u16* __restrict__ xb, const u32* __restrict__ img,
             const float* __restrict__ b1, const int* __restrict__ cnt,
             const int* __restrict__ tlist, const int* __restrict__ chunk2e,
             const int* __restrict__ chunkloc, u32* __restrict__ hid) {
  __shared__ u32 stg[2][4096];
  __shared__ int tkl[64];
  const int c = remap_chunk(blockIdx.x);
  const int e = chunk2e[c];
  if (e < 0) return;
  const int hc = blockIdx.y;
  const int loc = chunkloc[c];
  const int nt = cnt[e];
  const int tid = threadIdx.x;
  const int w = tid >> 6, lane = tid & 63;
  const int l15 = lane & 15, q = lane >> 4;
  const int wm = w & 1, wn = w >> 1;

  const u32* imgb = img + ((size_t)(e * 4 + hc) * 16) * 2048;
  auto stage = [&](int st, u32* dst) {
    const u32* src = imgb + st * 4096;
#pragma unroll
    for (int i = 0; i < 4; i++)
      gload_lds16(src + tid * 4 + i * 1024, dst + tid * 4 + i * 1024);
  };

  stage(0, stg[0]);
  if (tid < 64) {
    int i = min(loc * 64 + tid, nt - 1);
    tkl[tid] = tlist[(size_t)e * BT + i] >> 2;
  }
  __syncthreads();

  const int t0 = tkl[wn * 32 + l15];
  const int t1 = tkl[wn * 32 + 16 + l15];
  auto ldb = [&](int t, int st, int ss) {
    return *reinterpret_cast<const short8*>(
        xb + (size_t)t * 512 + st * 64 + ss * 32 + q * 8);
  };

  f32x4 acc[4][2];
#pragma unroll
  for (int a = 0; a < 4; a++)
#pragma unroll
    for (int b = 0; b < 2; b++) acc[a][b] = {0.f, 0.f, 0.f, 0.f};

  short8 bfr[2][2];
  bfr[0][0] = ldb(t0, 0, 0); bfr[0][1] = ldb(t0, 0, 1);
  bfr[1][0] = ldb(t1, 0, 0); bfr[1][1] = ldb(t1, 0, 1);

  for (int st = 0; st < 8; ++st) {
    const u32* cur = stg[st & 1];
    short8 nb[2][2];
    if (st < 7) {
      stage(st + 1, stg[(st + 1) & 1]);
      nb[0][0] = ldb(t0, st + 1, 0); nb[0][1] = ldb(t0, st + 1, 1);
      nb[1][0] = ldb(t1, st + 1, 0); nb[1][1] = ldb(t1, st + 1, 1);
    }
#pragma unroll
    for (int ss = 0; ss < 2; ++ss) {
#pragma unroll
      for (int mf = 0; mf < 4; ++mf) {
        int col = wm * 64 + mf * 16 + l15;
        short8 af = *reinterpret_cast<const short8*>(
            cur + ss * 2048 + q * 512 + col * 4);
        acc[mf][0] = __builtin_amdgcn_mfma_f32_16x16x32_bf16(af, bfr[0][ss], acc[mf][0], 0, 0, 0);
        acc[mf][1] = __builtin_amdgcn_mfma_f32_16x16x32_bf16(af, bfr[1][ss], acc[mf][1], 0, 0, 0);
      }
    }
    __syncthreads();
    if (st < 7) {
      bfr[0][0] = nb[0][0]; bfr[0][1] = nb[0][1];
      bfr[1][0] = nb[1][0]; bfr[1][1] = nb[1][1];
    }
  }

  const float* b1e = b1 + (size_t)e * HH;
#pragma unroll
  for (int mf = 0; mf < 4; ++mf) {
    int h0 = hc * 128 + wm * 64 + mf * 16 + q * 4;
    float4 bb = *reinterpret_cast<const float4*>(b1e + h0);
#pragma unroll
    for (int nf = 0; nf < 2; ++nf) {
      int local = wn * 32 + nf * 16 + l15;
      int prow = c * 64 + local;
      float v0 = fmaxf(acc[mf][nf].x + bb.x, 0.f);
      float v1 = fmaxf(acc[mf][nf].y + bb.y, 0.f);
      float v2 = fmaxf(acc[mf][nf].z + bb.z, 0.f);
      float v3 = fmaxf(acc[mf][nf].w + bb.w, 0.f);
      u32x2 pk = { pack2bf(v0, v1), pack2bf(v2, v3) };
      *reinterpret_cast<u32x2*>(hid + (size_t)prow * 256 + (h0 >> 1)) = pk;
    }
  }
}

// ---------------------------------------------------------------------------
// GEMM2 + fused confidence. Grid (MAXCH, 4).
// Phase 1 (all): oT tile = W2T . hidT -> bf16 o_p.
// Phase 2 (per-chunk winner via done2): conf MFMA for the chunk (reuses tke).
// ---------------------------------------------------------------------------
__global__ __launch_bounds__(256)
void k_gemm2c(const u32* __restrict__ hid, const u32* __restrict__ img,
              const float* __restrict__ b2, const int* __restrict__ cnt,
              const int* __restrict__ tlist, const int* __restrict__ chunk2e,
              const int* __restrict__ chunkloc, u16* __restrict__ o_p,
              const u32* __restrict__ img_c, const float* __restrict__ bc1,
              const float* __restrict__ Wc2, const float* __restrict__ bc2,
              const float* __restrict__ wts, int* __restrict__ done2,
              float* __restrict__ cw) {
  __shared__ u32 stg[2][4096];
  __shared__ int tke[64];
  __shared__ int cwin;
  const int c = remap_chunk(blockIdx.x);
  const int e = chunk2e[c];
  if (e < 0) return;
  const int dc = blockIdx.y;
  const int loc = chunkloc[c];
  const int nt = cnt[e];
  const int tid = threadIdx.x;
  const int w = tid >> 6, lane = tid & 63;
  const int l15 = lane & 15, q = lane >> 4;
  const int wm = w & 1, wn = w >> 1;
  const int rows_c = min(64, nt - loc * 64);

  const u32* imgb = img + ((size_t)((EE + e) * 4 + dc) * 16) * 2048;
  auto stage = [&](int st, u32* dst) {
    const u32* src = imgb + st * 4096;
#pragma unroll
    for (int i = 0; i < 4; i++)
      gload_lds16(src + tid * 4 + i * 1024, dst + tid * 4 + i * 1024);
  };

  stage(0, stg[0]);
  if (tid < 64) {
    int i = min(loc * 64 + tid, nt - 1);
    tke[tid] = tlist[(size_t)e * BT + i];
  }
  __syncthreads();

  const u16* hid16 = (const u16*)hid;
  const int pr0 = c * 64 + wn * 32 + l15;
  const int pr1 = pr0 + 16;
  auto ldb = [&](int pr, int st, int ss) {
    return *reinterpret_cast<const short8*>(
        hid16 + (size_t)pr * 512 + st * 64 + ss * 32 + q * 8);
  };

  f32x4 acc[4][2];
#pragma unroll
  for (int a = 0; a < 4; a++)
#pragma unroll
    for (int b = 0; b < 2; b++) acc[a][b] = {0.f, 0.f, 0.f, 0.f};

  short8 bfr[2][2];
  bfr[0][0] = ldb(pr0, 0, 0); bfr[0][1] = ldb(pr0, 0, 1);
  bfr[1][0] = ldb(pr1, 0, 0); bfr[1][1] = ldb(pr1, 0, 1);

  for (int st = 0; st < 8; ++st) {
    const u32* cur = stg[st & 1];
    short8 nb[2][2];
    if (st < 7) {
      stage(st + 1, stg[(st + 1) & 1]);
      nb[0][0] = ldb(pr0, st + 1, 0); nb[0][1] = ldb(pr0, st + 1, 1);
      nb[1][0] = ldb(pr1, st + 1, 0); nb[1][1] = ldb(pr1, st + 1, 1);
    }
#pragma unroll
    for (int ss = 0; ss < 2; ++ss) {
#pragma unroll
      for (int mf = 0; mf < 4; ++mf) {
        int col = wm * 64 + mf * 16 + l15;
        short8 af = *reinterpret_cast<const short8*>(
            cur + ss * 2048 + q * 512 + col * 4);
        acc[mf][0] = __builtin_amdgcn_mfma_f32_16x16x32_bf16(af, bfr[0][ss], acc[mf][0], 0, 0, 0);
        acc[mf][1] = __builtin_amdgcn_mfma_f32_16x16x32_bf16(af, bfr[1][ss], acc[mf][1], 0, 0, 0);
      }
    }
    __syncthreads();
    if (st < 7) {
      bfr[0][0] = nb[0][0]; bfr[0][1] = nb[0][1];
      bfr[1][0] = nb[1][0]; bfr[1][1] = nb[1][1];
    }
  }

  // epilogue: bias -> bf16 scatter to o_p
  const float* b2e = b2 + (size_t)e * DD;
#pragma unroll
  for (int mf = 0; mf < 4; ++mf) {
    int d0 = dc * 128 + wm * 64 + mf * 16 + q * 4;
    float4 bb = *reinterpret_cast<const float4*>(b2e + d0);
#pragma unroll
    for (int nf = 0; nf < 2; ++nf) {
      int local = wn * 32 + nf * 16 + l15;
      if (local < rows_c) {
        int ent = tke[local];
        u32x2 pk = { pack2bf(acc[mf][nf].x + bb.x, acc[mf][nf].y + bb.y),
                     pack2bf(acc[mf][nf].z + bb.z, acc[mf][nf].w + bb.w) };
        *reinterpret_cast<u32x2*>(&o_p[(size_t)ent * DD + d0]) = pk;
      }
    }
  }

  // ---------------- winner election for conf ----------------
  __threadfence();
  if (tid == 0) cwin = (atomicAdd(&done2[c], 1) == 3);
  __syncthreads();
  if (!cwin) return;
  __threadfence();

  // ---------------- conf phase (chunk winner; tke already in LDS) --------
  {
    u32* cs = &stg[0][0];   // 32 KB: full Wc1e image
    const u32* src = img_c + (size_t)e * 16 * 512;
#pragma unroll
    for (int i = 0; i < 8; ++i)
      gload_lds16(src + tid * 4 + i * 1024, cs + tid * 4 + i * 1024);
    __syncthreads();   // drains gload_lds

    const int local = w * 16 + l15;
    const int ent = tke[local];
    const u16* orow = o_p + (size_t)ent * DD;

    f32x4 acc0 = {0.f, 0.f, 0.f, 0.f}, acc1 = {0.f, 0.f, 0.f, 0.f};
#pragma unroll
    for (int st = 0; st < 16; ++st) {
      short8 bfrag = *reinterpret_cast<const short8*>(orow + st * 32 + q * 8);
      short8 af0 = *reinterpret_cast<const short8*>(
          cs + st * 512 + q * 128 + l15 * 4);
      short8 af1 = *reinterpret_cast<const short8*>(
          cs + st * 512 + q * 128 + (16 + l15) * 4);
      acc0 = __builtin_amdgcn_mfma_f32_16x16x32_bf16(af0, bfrag, acc0, 0, 0, 0);
      acc1 = __builtin_amdgcn_mfma_f32_16x16x32_bf16(af1, bfrag, acc1, 0, 0, 0);
    }

    float part = 0.f;
#pragma unroll
    for (int i = 0; i < 4; ++i) {
      int ch0 = q * 4 + i, ch1 = 16 + q * 4 + i;
      float h0 = fmaxf(acc0[i] + bc1[(size_t)e * CHN + ch0], 0.f);
      float h1 = fmaxf(acc1[i] + bc1[(size_t)e * CHN + ch1], 0.f);
      part = fmaf(h0, Wc2[(size_t)e * CHN + ch0], part);
      part = fmaf(h1, Wc2[(size_t)e * CHN + ch1], part);
    }
    part += __shfl_xor(part, 16);
    part += __shfl_xor(part, 32);
    if (q == 0 && local < rows_c) {
      float cv = 1.f / (1.f + expf(-(part + bc2[e])));
      cw[ent] = wts[(size_t)(ent >> 2) * EE + e] * cv;
    }
  }
}

// ---------------------------------------------------------------------------
// Combine: out[t] = sum_s cw*o / (sum_s cw + eps). o is bf16; 8 elems/thread.
// ---------------------------------------------------------------------------
__global__ __launch_bounds__(256)
void k_combine(const u16* __restrict__ o_p, const float* __restrict__ cw,
               float* __restrict__ out) {
  int gid = blockIdx.x * 256 + threadIdx.x;  // over B * (D/8)
  int t = gid >> 6;
  int j = gid & 63;
  float c0 = cw[t * 4 + 0], c1 = cw[t * 4 + 1];
  float c2 = cw[t * 4 + 2], c3 = cw[t * 4 + 3];
  float den = c0 + c1 + c2 + c3 + 1e-6f;
  const u16* base = o_p + (size_t)t * 4 * DD + j * 8;
  short8 v0 = *reinterpret_cast<const short8*>(base + 0 * DD);
  short8 v1 = *reinterpret_cast<const short8*>(base + 1 * DD);
  short8 v2 = *reinterpret_cast<const short8*>(base + 2 * DD);
  short8 v3 = *reinterpret_cast<const short8*>(base + 3 * DD);
  float r[8];
#pragma unroll
  for (int i = 0; i < 8; ++i) {
    r[i] = (c0 * bf16f((u16)v0[i]) + c1 * bf16f((u16)v1[i]) +
            c2 * bf16f((u16)v2[i]) + c3 * bf16f((u16)v3[i])) / den;
  }
  float4 o0 = { r[0], r[1], r[2], r[3] };
  float4 o1 = { r[4], r[5], r[6], r[7] };
  float4* dst = reinterpret_cast<float4*>(out + (size_t)t * DD + j * 8);
  dst[0] = o0;
  dst[1] = o1;
}

extern "C" void kernel_launch(void* const* d_in, const int* in_sizes, int n_in,
                              void* d_out, int out_size, void* d_ws, size_t ws_size,
                              hipStream_t stream) {
  const float* x   = (const float*)d_in[0];
  const float* W1  = (const float*)d_in[1];
  const float* b1  = (const float*)d_in[2];
  const float* W2  = (const float*)d_in[3];
  const float* b2  = (const float*)d_in[4];
  const float* Wg1 = (const float*)d_in[5];
  const float* bg1 = (const float*)d_in[6];
  const float* Wg2 = (const float*)d_in[7];
  const float* bg2 = (const float*)d_in[8];
  const float* Wc1 = (const float*)d_in[9];
  const float* bc1 = (const float*)d_in[10];
  const float* Wc2 = (const float*)d_in[11];
  const float* bc2 = (const float*)d_in[12];
  float* out = (float*)d_out;

  // workspace layout (~56 MB)
  char* p = (char*)d_ws;
  u16* xh = (u16*)p;            p += (size_t)BT * DD * 2;            // 2 MB
  u32* img = (u32*)p;           p += (size_t)66 * 4 * 16 * 2048 * 4; // 33 MB
  u16* hh = (u16*)p;                                                 // 2 MB (alias: dead before hid written)
  u16* hl = (u16*)(p + (size_t)2 * 1024 * 1024);                     // 2 MB
  u16* xl = (u16*)(p + (size_t)4 * 1024 * 1024);                     // 2 MB
  u32* hid = (u32*)p;           p += (size_t)MAXCH * 64 * DD * 2;    // 10.5 MB
  float* wts = (float*)p;       p += (size_t)BT * EE * 4;            // 256 KB
  float* cw  = (float*)p;       p += (size_t)BT * KK * 4;            // 32 KB
  u16* o_p = (u16*)p;           p += (size_t)BT * KK * DD * 2;       // 8 MB (bf16)
  int* cnt = (int*)p;           p += 256;
  int* tlist = (int*)p;         p += (size_t)EE * BT * 4;            // 256 KB
  int* chunk2e = (int*)p;       p += 1024;
  int* chunkloc = (int*)p;      p += 1024;
  u32* img_c = (u32*)p;         p += (size_t)34 * 16 * 512 * 4;      // 1.1 MB
  int* topi = (int*)p;          p += (size_t)BT * KK * 4;            // 32 KB
  int* flags = (int*)p;         p += 1024;  // done1[32] | gdone[1] | done2[160]
  int* done1 = flags;
  int* gdone = flags + 32;
  int* done2 = flags + 33;

  hipMemsetAsync(flags, 0, 1024, stream);
  k_prep<<<NB_PREP, 256, 0, stream>>>(x, W1, W2, Wc1, Wg1, Wg2,
                                      xh, xl, img, img_c);
  k_gate_fused<<<dim3(32, 8), 256, 0, stream>>>(xh, xl, img, bg1, img_c, bg2,
                                                hh, hl, wts, topi, done1, gdone,
                                                cnt, tlist, chunk2e, chunkloc);
  k_gemm1<<<dim3(MAXCH, 4), 256, 0, stream>>>(xh, img, b1, cnt, tlist,
                                              chunk2e, chunkloc, hid);
  k_gemm2c<<<dim3(MAXCH, 4), 256, 0, stream>>>(hid, img, b2, cnt, tlist,
                                               chunk2e, chunkloc, o_p,
                                               img_c, bc1, Wc2, bc2, wts,
                                               done2, cw);
  k_combine<<<(BT * (DD / 8)) / 256, 256, 0, stream>>>(o_p, cw, out);
}

// Round 17
// 103.230 us; speedup vs baseline: 2.1924x; 2.1924x over previous
//
#include <hip/hip_runtime.h>
#include <hip/hip_bf16.h>

// Problem constants
#define BT 2048   // batch
#define DD 512    // input dim
#define HH 512    // hidden dim
#define EE 32     // experts
#define KK 4      // top-k
#define CHN 32    // confidence hidden
#define MAXCH 160 // max 64-row chunks: 8192/64 + 32

// prep: cvt_x (512) | tr_wc (272: 34 imgs incl Wg2 hi/lo) | tr_w (66 z x 32)
#define NB_CVT 512
#define NB_TRWC 272
#define NB_TRW 2112
#define NB_PREP (NB_CVT + NB_TRWC + NB_TRW)

typedef unsigned int u32;
typedef unsigned short u16;
typedef __attribute__((ext_vector_type(8))) short short8;
typedef __attribute__((ext_vector_type(4))) float f32x4;
typedef __attribute__((ext_vector_type(2))) u32 u32x2;
typedef __attribute__((ext_vector_type(4))) u32 u32x4;

__device__ inline u16 f2bf(float f) {  // RNE float->bf16
  u32 u = __builtin_bit_cast(u32, f);
  u32 r = (u + 0x7FFFu + ((u >> 16) & 1u)) >> 16;
  return (u16)r;
}
__device__ inline float bf16f(u16 b) {  // bf16 -> float
  u32 u = ((u32)b) << 16;
  return __builtin_bit_cast(float, u);
}
__device__ inline u32 pack2bf(float a, float b) {
  return (u32)f2bf(a) | ((u32)f2bf(b) << 16);
}
__device__ inline void gload_lds16(const u32* g, u32* l) {
  __builtin_amdgcn_global_load_lds((const __attribute__((address_space(1))) u32*)g,
                                   (__attribute__((address_space(3))) u32*)l, 16, 0, 0);
}

// ---------------------------------------------------------------------------
// Fused prep (pure streaming, no LDS):
//  cvt_x: x -> bf16 hi (xh) + bf16 residual lo (xl)
//  tr_wc: Wc1 (e 0..31) + Wg2-hi (e=32) + Wg2-lo (e=33) conf-style images
//  tr_w:  z 0..31 W1 | 32..63 W2 | 64 Wg1-hi | 65 Wg1-lo  -> fraglet images
// ---------------------------------------------------------------------------
__global__ __launch_bounds__(256)
void k_prep(const float* __restrict__ x, const float* __restrict__ W1,
            const float* __restrict__ W2, const float* __restrict__ Wc1,
            const float* __restrict__ Wg1, const float* __restrict__ Wg2,
            u16* __restrict__ xh, u16* __restrict__ xl,
            u32* __restrict__ img, u32* __restrict__ img_c) {
  const int bx = blockIdx.x;
  const int tid = threadIdx.x;
  if (bx < NB_CVT) {
    // ---- cvt_x: hi + residual-lo ----
    int gid = bx * 256 + tid;
    const float4* src = reinterpret_cast<const float4*>(x) + (size_t)gid * 2;
    float4 a = src[0], b = src[1];
    u32x4 hi = { pack2bf(a.x, a.y), pack2bf(a.z, a.w),
                 pack2bf(b.x, b.y), pack2bf(b.z, b.w) };
    float lx0 = a.x - bf16f(f2bf(a.x)), lx1 = a.y - bf16f(f2bf(a.y));
    float lx2 = a.z - bf16f(f2bf(a.z)), lx3 = a.w - bf16f(f2bf(a.w));
    float lx4 = b.x - bf16f(f2bf(b.x)), lx5 = b.y - bf16f(f2bf(b.y));
    float lx6 = b.z - bf16f(f2bf(b.z)), lx7 = b.w - bf16f(f2bf(b.w));
    u32x4 lo = { pack2bf(lx0, lx1), pack2bf(lx2, lx3),
                 pack2bf(lx4, lx5), pack2bf(lx6, lx7) };
    reinterpret_cast<u32x4*>(xh)[gid] = hi;
    reinterpret_cast<u32x4*>(xl)[gid] = lo;
  } else if (bx < NB_CVT + NB_TRWC) {
    // ---- tr_wc: [512][32] fp32 -> k-major fraglet image (Wc1 / Wg2 hi/lo) --
    int idx = (bx - NB_CVT) * 2 + (tid >> 7);   // 0..543
    int e = idx >> 4, s = idx & 15;
    int t127 = tid & 127;
    int q = t127 >> 5, col = t127 & 31;
    const float* W = (e < EE) ? (Wc1 + (size_t)e * DD * CHN) : Wg2;
    float v[8];
#pragma unroll
    for (int j = 0; j < 8; ++j)
      v[j] = W[(size_t)(s * 32 + q * 8 + j) * CHN + col];
    if (e == 33) {
#pragma unroll
      for (int j = 0; j < 8; ++j)
        v[j] = v[j] - bf16f(f2bf(v[j]));      // exact residual
    }
    u32x4 fr = { pack2bf(v[0], v[1]), pack2bf(v[2], v[3]),
                 pack2bf(v[4], v[5]), pack2bf(v[6], v[7]) };
    *reinterpret_cast<u32x4*>(img_c + ((size_t)e * 16 + s) * 512 + q * 128 + col * 4) = fr;
  } else {
    // ---- tr_w: weight fraglet images (incl. Wg1 hi/lo at z=64/65) ----
    int u = bx - (NB_CVT + NB_TRWC);
    int z = u >> 5;
    int s = (u >> 1) & 15;
    int n = (u & 1) * 256 + tid;
    const float* W = (z < EE) ? (W1 + (size_t)z * DD * HH)
                   : (z < 2 * EE) ? (W2 + (size_t)(z - EE) * HH * DD)
                   : Wg1;
    float v[32];
#pragma unroll
    for (int k = 0; k < 32; k++)
      v[k] = W[(size_t)(s * 32 + k) * 512 + n];
    if (z == 65) {
#pragma unroll
      for (int k = 0; k < 32; k++)
        v[k] = v[k] - bf16f(f2bf(v[k]));
    }
    int nc = n >> 7, coll = n & 127;
    u32* ob = img + ((size_t)(z * 4 + nc) * 16 + s) * 2048 + coll * 4;
#pragma unroll
    for (int g = 0; g < 4; g++) {
      u32x4 fr = { pack2bf(v[g * 8 + 0], v[g * 8 + 1]),
                   pack2bf(v[g * 8 + 2], v[g * 8 + 3]),
                   pack2bf(v[g * 8 + 4], v[g * 8 + 5]),
                   pack2bf(v[g * 8 + 6], v[g * 8 + 7]) };
      *reinterpret_cast<u32x4*>(ob + g * 512) = fr;
    }
  }
}

// ---------------------------------------------------------------------------
// Gate hidden via MFMA, exact-split bf16 (4 cross terms). hidT = Wg1T . xT.
// Grid (32, 8), 256 thr. Output: h split into bf16 hi (hh) + residual (hl).
// ---------------------------------------------------------------------------
__global__ __launch_bounds__(256)
void k_gate_mfma(const u16* __restrict__ xh, const u16* __restrict__ xl,
                 const u32* __restrict__ img, const float* __restrict__ bg1,
                 u16* __restrict__ hh, u16* __restrict__ hl) {
  __shared__ u32 stg[2][2][1024];
  const int chunk = blockIdx.x;
  const int hc = blockIdx.y;
  const int tid = threadIdx.x;
  const int w = tid >> 6, lane = tid & 63;
  const int l15 = lane & 15, q = lane >> 4;
  const int wm = w & 1, wn = w >> 1;
  const int nc = hc >> 1, co = (hc & 1) * 64;
  const u32* imgh = img + ((size_t)(64 * 4 + nc) * 16) * 2048;
  const u32* imgl = img + ((size_t)(65 * 4 + nc) * 16) * 2048;
  const int sq = tid >> 6, scol = tid & 63;
  auto stage = [&](int s, int b) {
    gload_lds16(imgh + s * 2048 + sq * 512 + (co + scol) * 4, stg[b][0] + tid * 4);
    gload_lds16(imgl + s * 2048 + sq * 512 + (co + scol) * 4, stg[b][1] + tid * 4);
  };
  const int t0 = chunk * 64 + wn * 32 + l15;
  const int t1 = t0 + 16;
  auto ldb = [&](const u16* src, int t, int s) {
    return *reinterpret_cast<const short8*>(src + (size_t)t * 512 + s * 32 + q * 8);
  };

  f32x4 acc[2][2];
#pragma unroll
  for (int a = 0; a < 2; a++)
#pragma unroll
    for (int b = 0; b < 2; b++) acc[a][b] = {0.f, 0.f, 0.f, 0.f};

  stage(0, 0);
  short8 bh[2], bl[2];
  bh[0] = ldb(xh, t0, 0); bh[1] = ldb(xh, t1, 0);
  bl[0] = ldb(xl, t0, 0); bl[1] = ldb(xl, t1, 0);
  __syncthreads();

  for (int s = 0; s < 16; ++s) {
    const u32* ch = stg[s & 1][0];
    const u32* cl = stg[s & 1][1];
    short8 nh[2], nl[2];
    if (s < 15) {
      stage(s + 1, (s + 1) & 1);
      nh[0] = ldb(xh, t0, s + 1); nh[1] = ldb(xh, t1, s + 1);
      nl[0] = ldb(xl, t0, s + 1); nl[1] = ldb(xl, t1, s + 1);
    }
#pragma unroll
    for (int mf = 0; mf < 2; ++mf) {
      int col = wm * 32 + mf * 16 + l15;
      short8 ah = *reinterpret_cast<const short8*>(ch + q * 256 + col * 4);
      short8 al = *reinterpret_cast<const short8*>(cl + q * 256 + col * 4);
#pragma unroll
      for (int nf = 0; nf < 2; ++nf) {
        acc[mf][nf] = __builtin_amdgcn_mfma_f32_16x16x32_bf16(ah, bh[nf], acc[mf][nf], 0, 0, 0);
        acc[mf][nf] = __builtin_amdgcn_mfma_f32_16x16x32_bf16(ah, bl[nf], acc[mf][nf], 0, 0, 0);
        acc[mf][nf] = __builtin_amdgcn_mfma_f32_16x16x32_bf16(al, bh[nf], acc[mf][nf], 0, 0, 0);
        acc[mf][nf] = __builtin_amdgcn_mfma_f32_16x16x32_bf16(al, bl[nf], acc[mf][nf], 0, 0, 0);
      }
    }
    __syncthreads();
    if (s < 15) {
      bh[0] = nh[0]; bh[1] = nh[1];
      bl[0] = nl[0]; bl[1] = nl[1];
    }
  }

  // epilogue: bias + relu -> split bf16 hi/lo
#pragma unroll
  for (int mf = 0; mf < 2; ++mf) {
    int hcol = hc * 64 + wm * 32 + mf * 16 + q * 4;
    float4 bb = *reinterpret_cast<const float4*>(&bg1[hcol]);
#pragma unroll
    for (int nf = 0; nf < 2; ++nf) {
      int t = chunk * 64 + wn * 32 + nf * 16 + l15;
      float v0 = fmaxf(acc[mf][nf].x + bb.x, 0.f);
      float v1 = fmaxf(acc[mf][nf].y + bb.y, 0.f);
      float v2 = fmaxf(acc[mf][nf].z + bb.z, 0.f);
      float v3 = fmaxf(acc[mf][nf].w + bb.w, 0.f);
      u32x2 hi = { pack2bf(v0, v1), pack2bf(v2, v3) };
      float r0 = v0 - bf16f(f2bf(v0)), r1 = v1 - bf16f(f2bf(v1));
      float r2 = v2 - bf16f(f2bf(v2)), r3 = v3 - bf16f(f2bf(v3));
      u32x2 lo = { pack2bf(r0, r1), pack2bf(r2, r3) };
      *reinterpret_cast<u32x2*>(hh + (size_t)t * 512 + hcol) = hi;
      *reinterpret_cast<u32x2*>(hl + (size_t)t * 512 + hcol) = lo;
    }
  }
}

// ---------------------------------------------------------------------------
// Route via MFMA: logits = h @ Wg2, exact-split both sides (4 cross terms),
// in-register softmax + top-4. 32 blocks x 64 tokens.
// ---------------------------------------------------------------------------
__global__ __launch_bounds__(256)
void k_route2(const u16* __restrict__ hh, const u16* __restrict__ hl,
              const u32* __restrict__ img_c, const float* __restrict__ bg2,
              float* __restrict__ wts, int* __restrict__ topi) {
  __shared__ u32 sh[8192];   // Wg2-hi image (32 KB)
  __shared__ u32 sl_[8192];  // Wg2-lo image (32 KB)
  const int chunk = blockIdx.x;
  const int tid = threadIdx.x;
  const int w = tid >> 6, lane = tid & 63;
  const int l15 = lane & 15, q = lane >> 4;
  const u32* srch = img_c + (size_t)32 * 16 * 512;
  const u32* srcl = img_c + (size_t)33 * 16 * 512;
#pragma unroll
  for (int i = 0; i < 8; ++i) {
    gload_lds16(srch + tid * 4 + i * 1024, sh + tid * 4 + i * 1024);
    gload_lds16(srcl + tid * 4 + i * 1024, sl_ + tid * 4 + i * 1024);
  }
  __syncthreads();

  const int t = chunk * 64 + w * 16 + l15;
  const u16* rh = hh + (size_t)t * 512;
  const u16* rl = hl + (size_t)t * 512;
  f32x4 acc0 = {0.f, 0.f, 0.f, 0.f}, acc1 = {0.f, 0.f, 0.f, 0.f};
#pragma unroll
  for (int st = 0; st < 16; ++st) {
    short8 bh = *reinterpret_cast<const short8*>(rh + st * 32 + q * 8);
    short8 bl = *reinterpret_cast<const short8*>(rl + st * 32 + q * 8);
    short8 ah0 = *reinterpret_cast<const short8*>(sh + st * 512 + q * 128 + l15 * 4);
    short8 ah1 = *reinterpret_cast<const short8*>(sh + st * 512 + q * 128 + (16 + l15) * 4);
    short8 al0 = *reinterpret_cast<const short8*>(sl_ + st * 512 + q * 128 + l15 * 4);
    short8 al1 = *reinterpret_cast<const short8*>(sl_ + st * 512 + q * 128 + (16 + l15) * 4);
    acc0 = __builtin_amdgcn_mfma_f32_16x16x32_bf16(ah0, bh, acc0, 0, 0, 0);
    acc0 = __builtin_amdgcn_mfma_f32_16x16x32_bf16(ah0, bl, acc0, 0, 0, 0);
    acc0 = __builtin_amdgcn_mfma_f32_16x16x32_bf16(al0, bh, acc0, 0, 0, 0);
    acc0 = __builtin_amdgcn_mfma_f32_16x16x32_bf16(al0, bl, acc0, 0, 0, 0);
    acc1 = __builtin_amdgcn_mfma_f32_16x16x32_bf16(ah1, bh, acc1, 0, 0, 0);
    acc1 = __builtin_amdgcn_mfma_f32_16x16x32_bf16(ah1, bl, acc1, 0, 0, 0);
    acc1 = __builtin_amdgcn_mfma_f32_16x16x32_bf16(al1, bh, acc1, 0, 0, 0);
    acc1 = __builtin_amdgcn_mfma_f32_16x16x32_bf16(al1, bl, acc1, 0, 0, 0);
  }

  float lv[8];
  int li[8];
#pragma unroll
  for (int i = 0; i < 4; ++i) {
    li[i] = q * 4 + i;
    lv[i] = acc0[i] + bg2[li[i]];
    li[4 + i] = 16 + q * 4 + i;
    lv[4 + i] = acc1[i] + bg2[li[4 + i]];
  }
  float mx = lv[0];
#pragma unroll
  for (int k = 1; k < 8; ++k) mx = fmaxf(mx, lv[k]);
  mx = fmaxf(mx, __shfl_xor(mx, 16));
  mx = fmaxf(mx, __shfl_xor(mx, 32));
  float ex[8], sm = 0.f;
#pragma unroll
  for (int k = 0; k < 8; ++k) { ex[k] = expf(lv[k] - mx); sm += ex[k]; }
  sm += __shfl_xor(sm, 16);
  sm += __shfl_xor(sm, 32);
  float inv = 1.f / sm;
  float4 w0 = { ex[0] * inv, ex[1] * inv, ex[2] * inv, ex[3] * inv };
  float4 w1 = { ex[4] * inv, ex[5] * inv, ex[6] * inv, ex[7] * inv };
  *reinterpret_cast<float4*>(&wts[(size_t)t * EE + q * 4]) = w0;
  *reinterpret_cast<float4*>(&wts[(size_t)t * EE + 16 + q * 4]) = w1;
  unsigned used = 0;
  for (int j = 0; j < KK; ++j) {
    float bv = -1e30f;
    int bi = 64;
#pragma unroll
    for (int k = 0; k < 8; ++k) {
      if (!((used >> k) & 1u) && (lv[k] > bv || (lv[k] == bv && li[k] < bi))) {
        bv = lv[k]; bi = li[k];
      }
    }
#pragma unroll
    for (int m = 16; m <= 32; m <<= 1) {
      float ov = __shfl_xor(bv, m);
      int oi = __shfl_xor(bi, m);
      if (ov > bv || (ov == bv && oi < bi)) { bv = ov; bi = oi; }
    }
    if (q == 0) topi[(t << 2) | j] = bi;
#pragma unroll
    for (int k = 0; k < 8; ++k)
      if (li[k] == bi) used |= 1u << k;
  }
}

// ---------------------------------------------------------------------------
// Build routing lists + chunk tables from topi. One block, 1024 thr.
// ---------------------------------------------------------------------------
__global__ __launch_bounds__(1024)
void k_build(const int* __restrict__ topi, int* __restrict__ cnt,
             int* __restrict__ tlist, int* __restrict__ chunk2e,
             int* __restrict__ chunkloc) {
  __shared__ int lcnt[EE];
  const int tid = threadIdx.x;
  if (tid < EE) lcnt[tid] = 0;
  __syncthreads();
  for (int i = tid; i < BT * KK; i += 1024) {
    int e = topi[i];
    int pos = atomicAdd(&lcnt[e], 1);
    tlist[(size_t)e * BT + pos] = i;
  }
  __syncthreads();
  if (tid < EE) {
    int e = tid;
    cnt[e] = lcnt[e];
    int off = 0, tot = 0;
    for (int j = 0; j < EE; ++j) {
      int nj = (lcnt[j] + 63) >> 6;
      if (j < e) off += nj;
      tot += nj;
    }
    int myn = (lcnt[e] + 63) >> 6;
    for (int j = 0; j < myn; ++j) {
      chunk2e[off + j] = e; chunkloc[off + j] = j;
    }
    for (int idx = tot + e; idx < MAXCH; idx += EE) {
      chunk2e[idx] = -1; chunkloc[idx] = 0;
    }
  }
}

// XCD-affinity chunk remap.
__device__ inline int remap_chunk(int bx) {
  return (bx & 7) * (MAXCH / 8) + (bx >> 3);
}

// ---------------------------------------------------------------------------
// GEMM1 (grouped, swapped): hidT = W1T(512h x 512k) . xT(512k x 64t).
// ---------------------------------------------------------------------------
__global__ __launch_bounds__(256)
void k_gemm1(const u16* __restrict__ xb, const u32* __restrict__ img,
             const float* __restrict__ b1, const int* __restrict__ cnt,
             const int* __restrict__ tlist, const int* __restrict__ chunk2e,
             const int* __restrict__ chunkloc, u32* __restrict__ hid) {
  __shared__ u32 stg[2][4096];
  __shared__ int tkl[64];
  const int c = remap_chunk(blockIdx.x);
  const int e = chunk2e[c];
  if (e < 0) return;
  const int hc = blockIdx.y;
  const int loc = chunkloc[c];
  const int nt = cnt[e];
  const int tid = threadIdx.x;
  const int w = tid >> 6, lane = tid & 63;
  const int l15 = lane & 15, q = lane >> 4;
  const int wm = w & 1, wn = w >> 1;

  const u32* imgb = img + ((size_t)(e * 4 + hc) * 16) * 2048;
  auto stage = [&](int st, u32* dst) {
    const u32* src = imgb + st * 4096;
#pragma unroll
    for (int i = 0; i < 4; i++)
      gload_lds16(src + tid * 4 + i * 1024, dst + tid * 4 + i * 1024);
  };

  stage(0, stg[0]);
  if (tid < 64) {
    int i = min(loc * 64 + tid, nt - 1);
    tkl[tid] = tlist[(size_t)e * BT + i] >> 2;
  }
  __syncthreads();

  const int t0 = tkl[wn * 32 + l15];
  const int t1 = tkl[wn * 32 + 16 + l15];
  auto ldb = [&](int t, int st, int ss) {
    return *reinterpret_cast<const short8*>(
        xb + (size_t)t * 512 + st * 64 + ss * 32 + q * 8);
  };

  f32x4 acc[4][2];
#pragma unroll
  for (int a = 0; a < 4; a++)
#pragma unroll
    for (int b = 0; b < 2; b++) acc[a][b] = {0.f, 0.f, 0.f, 0.f};

  short8 bfr[2][2];
  bfr[0][0] = ldb(t0, 0, 0); bfr[0][1] = ldb(t0, 0, 1);
  bfr[1][0] = ldb(t1, 0, 0); bfr[1][1] = ldb(t1, 0, 1);

  for (int st = 0; st < 8; ++st) {
    const u32* cur = stg[st & 1];
    short8 nb[2][2];
    if (st < 7) {
      stage(st + 1, stg[(st + 1) & 1]);
      nb[0][0] = ldb(t0, st + 1, 0); nb[0][1] = ldb(t0, st + 1, 1);
      nb[1][0] = ldb(t1, st + 1, 0); nb[1][1] = ldb(t1, st + 1, 1);
    }
#pragma unroll
    for (int ss = 0; ss < 2; ++ss) {
#pragma unroll
      for (int mf = 0; mf < 4; ++mf) {
        int col = wm * 64 + mf * 16 + l15;
        short8 af = *reinterpret_cast<const short8*>(
            cur + ss * 2048 + q * 512 + col * 4);
        acc[mf][0] = __builtin_amdgcn_mfma_f32_16x16x32_bf16(af, bfr[0][ss], acc[mf][0], 0, 0, 0);
        acc[mf][1] = __builtin_amdgcn_mfma_f32_16x16x32_bf16(af, bfr[1][ss], acc[mf][1], 0, 0, 0);
      }
    }
    __syncthreads();
    if (st < 7) {
      bfr[0][0] = nb[0][0]; bfr[0][1] = nb[0][1];
      bfr[1][0] = nb[1][0]; bfr[1][1] = nb[1][1];
    }
  }

  const float* b1e = b1 + (size_t)e * HH;
#pragma unroll
  for (int mf = 0; mf < 4; ++mf) {
    int h0 = hc * 128 + wm * 64 + mf * 16 + q * 4;
    float4 bb = *reinterpret_cast<const float4*>(b1e + h0);
#pragma unroll
    for (int nf = 0; nf < 2; ++nf) {
      int local = wn * 32 + nf * 16 + l15;
      int prow = c * 64 + local;
      float v0 = fmaxf(acc[mf][nf].x + bb.x, 0.f);
      float v1 = fmaxf(acc[mf][nf].y + bb.y, 0.f);
      float v2 = fmaxf(acc[mf][nf].z + bb.z, 0.f);
      float v3 = fmaxf(acc[mf][nf].w + bb.w, 0.f);
      u32x2 pk = { pack2bf(v0, v1), pack2bf(v2, v3) };
      *reinterpret_cast<u32x2*>(hid + (size_t)prow * 256 + (h0 >> 1)) = pk;
    }
  }
}

// ---------------------------------------------------------------------------
// GEMM2 (grouped, swapped): oT = W2T(512d x 512h) . hidT(512h x 64t).
// Epilogue stores o as bf16 (conf2 quantized to bf16 anyway; combine margin ok)
// ---------------------------------------------------------------------------
__global__ __launch_bounds__(256)
void k_gemm2(const u32* __restrict__ hid, const u32* __restrict__ img,
             const float* __restrict__ b2, const int* __restrict__ cnt,
             const int* __restrict__ tlist, const int* __restrict__ chunk2e,
             const int* __restrict__ chunkloc, u16* __restrict__ o_p) {
  __shared__ u32 stg[2][4096];
  __shared__ int tke[64];
  const int c = remap_chunk(blockIdx.x);
  const int e = chunk2e[c];
  if (e < 0) return;
  const int dc = blockIdx.y;
  const int loc = chunkloc[c];
  const int nt = cnt[e];
  const int tid = threadIdx.x;
  const int w = tid >> 6, lane = tid & 63;
  const int l15 = lane & 15, q = lane >> 4;
  const int wm = w & 1, wn = w >> 1;
  const int rows_c = min(64, nt - loc * 64);

  const u32* imgb = img + ((size_t)((EE + e) * 4 + dc) * 16) * 2048;
  auto stage = [&](int st, u32* dst) {
    const u32* src = imgb + st * 4096;
#pragma unroll
    for (int i = 0; i < 4; i++)
      gload_lds16(src + tid * 4 + i * 1024, dst + tid * 4 + i * 1024);
  };

  stage(0, stg[0]);
  if (tid < 64) {
    int i = min(loc * 64 + tid, nt - 1);
    tke[tid] = tlist[(size_t)e * BT + i];
  }
  __syncthreads();

  const u16* hid16 = (const u16*)hid;
  const int pr0 = c * 64 + wn * 32 + l15;
  const int pr1 = pr0 + 16;
  auto ldb = [&](int pr, int st, int ss) {
    return *reinterpret_cast<const short8*>(
        hid16 + (size_t)pr * 512 + st * 64 + ss * 32 + q * 8);
  };

  f32x4 acc[4][2];
#pragma unroll
  for (int a = 0; a < 4; a++)
#pragma unroll
    for (int b = 0; b < 2; b++) acc[a][b] = {0.f, 0.f, 0.f, 0.f};

  short8 bfr[2][2];
  bfr[0][0] = ldb(pr0, 0, 0); bfr[0][1] = ldb(pr0, 0, 1);
  bfr[1][0] = ldb(pr1, 0, 0); bfr[1][1] = ldb(pr1, 0, 1);

  for (int st = 0; st < 8; ++st) {
    const u32* cur = stg[st & 1];
    short8 nb[2][2];
    if (st < 7) {
      stage(st + 1, stg[(st + 1) & 1]);
      nb[0][0] = ldb(pr0, st + 1, 0); nb[0][1] = ldb(pr0, st + 1, 1);
      nb[1][0] = ldb(pr1, st + 1, 0); nb[1][1] = ldb(pr1, st + 1, 1);
    }
#pragma unroll
    for (int ss = 0; ss < 2; ++ss) {
#pragma unroll
      for (int mf = 0; mf < 4; ++mf) {
        int col = wm * 64 + mf * 16 + l15;
        short8 af = *reinterpret_cast<const short8*>(
            cur + ss * 2048 + q * 512 + col * 4);
        acc[mf][0] = __builtin_amdgcn_mfma_f32_16x16x32_bf16(af, bfr[0][ss], acc[mf][0], 0, 0, 0);
        acc[mf][1] = __builtin_amdgcn_mfma_f32_16x16x32_bf16(af, bfr[1][ss], acc[mf][1], 0, 0, 0);
      }
    }
    __syncthreads();
    if (st < 7) {
      bfr[0][0] = nb[0][0]; bfr[0][1] = nb[0][1];
      bfr[1][0] = nb[1][0]; bfr[1][1] = nb[1][1];
    }
  }

  // epilogue: bias -> bf16 scatter to o_p[(t*K+slot)*D + d] (skip pad rows)
  const float* b2e = b2 + (size_t)e * DD;
#pragma unroll
  for (int mf = 0; mf < 4; ++mf) {
    int d0 = dc * 128 + wm * 64 + mf * 16 + q * 4;
    float4 bb = *reinterpret_cast<const float4*>(b2e + d0);
#pragma unroll
    for (int nf = 0; nf < 2; ++nf) {
      int local = wn * 32 + nf * 16 + l15;
      if (local < rows_c) {
        int ent = tke[local];
        u32x2 pk = { pack2bf(acc[mf][nf].x + bb.x, acc[mf][nf].y + bb.y),
                     pack2bf(acc[mf][nf].z + bb.z, acc[mf][nf].w + bb.w) };
        *reinterpret_cast<u32x2*>(&o_p[(size_t)ent * DD + d0]) = pk;
      }
    }
  }
}

// ---------------------------------------------------------------------------
// Confidence via MFMA. One block per 64-token chunk, 256 thr (4 waves).
// o_p is bf16 -> B-fragments load directly (no packing).
// ---------------------------------------------------------------------------
__global__ __launch_bounds__(256)
void k_conf2(const u16* __restrict__ o_p, const u32* __restrict__ img_c,
             const float* __restrict__ bc1, const float* __restrict__ Wc2,
             const float* __restrict__ bc2, const float* __restrict__ wts,
             const int* __restrict__ cnt, const int* __restrict__ tlist,
             const int* __restrict__ chunk2e, const int* __restrict__ chunkloc,
             float* __restrict__ cw) {
  __shared__ u32 stg[8192];
  __shared__ int tke[64];
  const int c = remap_chunk(blockIdx.x);
  const int e = chunk2e[c];
  if (e < 0) return;
  const int loc = chunkloc[c];
  const int nt = cnt[e];
  const int tid = threadIdx.x;
  const int w = tid >> 6, lane = tid & 63;
  const int l15 = lane & 15, q = lane >> 4;

  const u32* src = img_c + (size_t)e * 16 * 512;
#pragma unroll
  for (int i = 0; i < 8; ++i)
    gload_lds16(src + tid * 4 + i * 1024, stg + tid * 4 + i * 1024);
  if (tid < 64) {
    int i = min(loc * 64 + tid, nt - 1);
    tke[tid] = tlist[(size_t)e * BT + i];
  }
  __syncthreads();

  const int rows_c = min(64, nt - loc * 64);
  const int local = w * 16 + l15;
  const int ent = tke[local];
  const u16* orow = o_p + (size_t)ent * DD;

  f32x4 acc0 = {0.f, 0.f, 0.f, 0.f}, acc1 = {0.f, 0.f, 0.f, 0.f};
#pragma unroll
  for (int st = 0; st < 16; ++st) {
    short8 bfrag = *reinterpret_cast<const short8*>(orow + st * 32 + q * 8);
    short8 af0 = *reinterpret_cast<const short8*>(
        stg + st * 512 + q * 128 + l15 * 4);
    short8 af1 = *reinterpret_cast<const short8*>(
        stg + st * 512 + q * 128 + (16 + l15) * 4);
    acc0 = __builtin_amdgcn_mfma_f32_16x16x32_bf16(af0, bfrag, acc0, 0, 0, 0);
    acc1 = __builtin_amdgcn_mfma_f32_16x16x32_bf16(af1, bfrag, acc1, 0, 0, 0);
  }

  float part = 0.f;
#pragma unroll
  for (int i = 0; i < 4; ++i) {
    int ch0 = q * 4 + i, ch1 = 16 + q * 4 + i;
    float h0 = fmaxf(acc0[i] + bc1[(size_t)e * CHN + ch0], 0.f);
    float h1 = fmaxf(acc1[i] + bc1[(size_t)e * CHN + ch1], 0.f);
    part = fmaf(h0, Wc2[(size_t)e * CHN + ch0], part);
    part = fmaf(h1, Wc2[(size_t)e * CHN + ch1], part);
  }
  part += __shfl_xor(part, 16);
  part += __shfl_xor(part, 32);
  if (q == 0 && local < rows_c) {
    float cv = 1.f / (1.f + expf(-(part + bc2[e])));
    cw[ent] = wts[(size_t)(ent >> 2) * EE + e] * cv;
  }
}

// ---------------------------------------------------------------------------
// Combine: out[t] = sum_s cw*o / (sum_s cw + eps). o is bf16; 8 elems/thread.
// ---------------------------------------------------------------------------
__global__ __launch_bounds__(256)
void k_combine(const u16* __restrict__ o_p, const float* __restrict__ cw,
               float* __restrict__ out) {
  int gid = blockIdx.x * 256 + threadIdx.x;  // over B * (D/8)
  int t = gid >> 6;
  int j = gid & 63;                           // 8-elem group
  float c0 = cw[t * 4 + 0], c1 = cw[t * 4 + 1];
  float c2 = cw[t * 4 + 2], c3 = cw[t * 4 + 3];
  float den = c0 + c1 + c2 + c3 + 1e-6f;
  const u16* base = o_p + (size_t)t * 4 * DD + j * 8;
  short8 v0 = *reinterpret_cast<const short8*>(base + 0 * DD);
  short8 v1 = *reinterpret_cast<const short8*>(base + 1 * DD);
  short8 v2 = *reinterpret_cast<const short8*>(base + 2 * DD);
  short8 v3 = *reinterpret_cast<const short8*>(base + 3 * DD);
  float r[8];
#pragma unroll
  for (int i = 0; i < 8; ++i) {
    r[i] = (c0 * bf16f((u16)v0[i]) + c1 * bf16f((u16)v1[i]) +
            c2 * bf16f((u16)v2[i]) + c3 * bf16f((u16)v3[i])) / den;
  }
  float4 o0 = { r[0], r[1], r[2], r[3] };
  float4 o1 = { r[4], r[5], r[6], r[7] };
  float4* dst = reinterpret_cast<float4*>(out + (size_t)t * DD + j * 8);
  dst[0] = o0;
  dst[1] = o1;
}

extern "C" void kernel_launch(void* const* d_in, const int* in_sizes, int n_in,
                              void* d_out, int out_size, void* d_ws, size_t ws_size,
                              hipStream_t stream) {
  const float* x   = (const float*)d_in[0];
  const float* W1  = (const float*)d_in[1];
  const float* b1  = (const float*)d_in[2];
  const float* W2  = (const float*)d_in[3];
  const float* b2  = (const float*)d_in[4];
  const float* Wg1 = (const float*)d_in[5];
  const float* bg1 = (const float*)d_in[6];
  const float* Wg2 = (const float*)d_in[7];
  const float* bg2 = (const float*)d_in[8];
  const float* Wc1 = (const float*)d_in[9];
  const float* bc1 = (const float*)d_in[10];
  const float* Wc2 = (const float*)d_in[11];
  const float* bc2 = (const float*)d_in[12];
  float* out = (float*)d_out;

  // workspace layout (~56 MB)
  char* p = (char*)d_ws;
  u16* xh = (u16*)p;            p += (size_t)BT * DD * 2;            // 2 MB
  u32* img = (u32*)p;           p += (size_t)66 * 4 * 16 * 2048 * 4; // 33 MB
  u16* hh = (u16*)p;                                                 // 2 MB  (alias: dead before hid written)
  u16* hl = (u16*)(p + (size_t)2 * 1024 * 1024);                     // 2 MB
  u16* xl = (u16*)(p + (size_t)4 * 1024 * 1024);                     // 2 MB
  u32* hid = (u32*)p;           p += (size_t)MAXCH * 64 * DD * 2;    // 10.5 MB
  float* wts = (float*)p;       p += (size_t)BT * EE * 4;            // 256 KB
  float* cw  = (float*)p;       p += (size_t)BT * KK * 4;            // 32 KB
  u16* o_p = (u16*)p;           p += (size_t)BT * KK * DD * 2;       // 8 MB (bf16)
  int* cnt = (int*)p;           p += 256;
  int* tlist = (int*)p;         p += (size_t)EE * BT * 4;            // 256 KB
  int* chunk2e = (int*)p;       p += 1024;
  int* chunkloc = (int*)p;      p += 1024;
  u32* img_c = (u32*)p;         p += (size_t)34 * 16 * 512 * 4;      // 1.1 MB
  int* topi = (int*)p;          p += (size_t)BT * KK * 4;            // 32 KB

  k_prep<<<NB_PREP, 256, 0, stream>>>(x, W1, W2, Wc1, Wg1, Wg2,
                                      xh, xl, img, img_c);
  k_gate_mfma<<<dim3(32, 8), 256, 0, stream>>>(xh, xl, img, bg1, hh, hl);
  k_route2<<<32, 256, 0, stream>>>(hh, hl, img_c, bg2, wts, topi);
  k_build<<<1, 1024, 0, stream>>>(topi, cnt, tlist, chunk2e, chunkloc);
  k_gemm1<<<dim3(MAXCH, 4), 256, 0, stream>>>(xh, img, b1, cnt, tlist,
                                              chunk2e, chunkloc, hid);
  k_gemm2<<<dim3(MAXCH, 4), 256, 0, stream>>>(hid, img, b2, cnt, tlist,
                                              chunk2e, chunkloc, o_p);
  k_conf2<<<MAXCH, 256, 0, stream>>>(o_p, img_c, bc1, Wc2, bc2, wts,
                                     cnt, tlist, chunk2e, chunkloc, cw);
  k_combine<<<(BT * (DD / 8)) / 256, 256, 0, stream>>>(o_p, cw, out);
}